// Round 7
// baseline (61.335 us; speedup 1.0000x reference)
//
#include <hip/hip_runtime.h>
#include <math.h>

#define NB 4
#define TTEXT 160
#define TFEAT 800

typedef __bf16 bf16x8 __attribute__((ext_vector_type(8)));
typedef float f32x4 __attribute__((ext_vector_type(4)));

__device__ inline unsigned short f2bf(float f) {
    unsigned int u = __builtin_bit_cast(unsigned int, f);
    unsigned int r = u + 0x7fffu + ((u >> 16) & 1u);
    return (unsigned short)(r >> 16);
}
__device__ inline float bf2f(unsigned short h) {
    unsigned int u = ((unsigned int)h) << 16;
    return __builtin_bit_cast(float, u);
}

// ---------------------------------------------------------------------------
// Prep: flat exact-size grid (2340 blocks = 599040 threads). Weight
// transforms into B-fragment-native layout Wb[c][co][q] + lgamma table.
// Block 0 also zeroes the inter-block flags (fresh every call -> the fused
// kernel's atomic counters are re-armed; stream order makes this visible).
// ---------------------------------------------------------------------------
__global__ __launch_bounds__(256) void prep_kernel(
    const float* __restrict__ tw1, const float* __restrict__ tw2,
    const float* __restrict__ fw1, const float* __restrict__ fw2,
    const float* __restrict__ fw3,
    unsigned short* __restrict__ wb_t1, unsigned short* __restrict__ wb_t2,
    unsigned short* __restrict__ wb_f1, unsigned short* __restrict__ wb_f2,
    unsigned short* __restrict__ wb_f3, float* __restrict__ lg,
    int* __restrict__ flags)
{
    if (blockIdx.x == 0 && threadIdx.x < 16) flags[threadIdx.x] = 0;
    const int u = blockIdx.x * 256 + threadIdx.x;
    if (u >= 598016) {
        const int n = u - 598016;
        if (n < 1024) lg[n] = (n >= 1) ? (float)lgamma((double)n) : 0.0f;
        return;
    }
    int rem = u;
    int CIN, CINP, K; const float* src; unsigned short* dst;
    if (rem < 196608)                  { CIN = 256; CINP = 256; K = 3; src = tw1; dst = wb_t1; }
    else if ((rem -= 196608) < 65536)  { CIN = 256; CINP = 256; K = 1; src = tw2; dst = wb_t2; }
    else if ((rem -= 65536) < 73728)   { CIN = 80;  CINP = 96;  K = 3; src = fw1; dst = wb_f1; }
    else if ((rem -= 73728) < 196608)  { CIN = 256; CINP = 256; K = 3; src = fw2; dst = wb_f2; }
    else { rem -= 196608;                CIN = 256; CINP = 256; K = 1; src = fw3; dst = wb_f3; }
    const int q = rem & 31, coc = rem >> 5, co = coc & 255, c = coc >> 8;
    const int cpk = CINP / 32, k = c / cpk, ci = (c % cpk) * 32 + q;
    const float v = (ci < CIN) ? src[((size_t)co * CIN + ci) * K + k] : 0.0f;
    dst[rem] = f2bf(v);
}

// ---------------------------------------------------------------------------
// Fused stems + score, 240 blocks x 512 threads (8 waves; wave w owns 32
// output channels in the stem phases).
//   blocks  0..39 : text stem -> tB,tnorm (global) -> threadfence ->
//                   atomicAdd(flag[b])  (10 blocks per batch)
//   blocks 40..239: feats stem (f3 output + fnorm stay in LDS) -> wait for
//                   flag[b]==10 -> score: A-frags from LDS, 10 N-frags
//                   spread {2,2,1,1,1,1,1,1} over the 8 waves, 2-barrier
//                   LDS softmax, prior, store.
// Producer blocks have LOWER blockIdx than consumers (in-order dispatch =>
// deadlock-free); 240 blocks <= 256 CUs are co-resident anyway.
// ---------------------------------------------------------------------------
__global__ __launch_bounds__(512) void fused_kernel(
    const float* __restrict__ text, const float* __restrict__ feats,
    const unsigned char* __restrict__ xmask,
    const unsigned short* __restrict__ wt1, const float* __restrict__ bt1,
    const unsigned short* __restrict__ wt2, const float* __restrict__ bt2,
    const unsigned short* __restrict__ wf1, const float* __restrict__ bf1v,
    const unsigned short* __restrict__ wf2, const float* __restrict__ bf2v,
    const unsigned short* __restrict__ wf3, const float* __restrict__ bf3v,
    const float* __restrict__ lg,
    unsigned short* __restrict__ tB, float* __restrict__ tnorm,
    int* __restrict__ flags, float* __restrict__ out)
{
    __shared__ __align__(16) unsigned short s[11056];
    __shared__ float s_red[16][8];
    __shared__ float s_red2[16][8];
    __shared__ float s_fn[16];
    const int tid = threadIdx.x;
    const int w  = tid >> 6;        // 0..7
    const int l  = tid & 63;
    const int lr = l & 15;
    const int lk = l >> 4;
    const int co0 = w * 32;         // stem: 32 channels per wave
    const int koff = lk * 8;
    const int bid = blockIdx.x;

    if (bid < 40) {
        // ------------------------- text stem -------------------------
        const int b  = bid & 3;
        const int t0 = (bid >> 2) << 4;
        unsigned short* s_in  = s;          // [18][264]
        unsigned short* s_mid = s + 4752;   // [16][264]

        for (int idx = tid; idx < 18 * 64; idx += 512) {
            const int r = idx >> 6, c4 = idx & 63;
            const int x = t0 - 1 + r;
            float4 v = {0.f, 0.f, 0.f, 0.f};
            if (x >= 0 && x < TTEXT)
                v = *(const float4*)(text + ((size_t)(b * TTEXT + x)) * 256 + c4 * 4);
            unsigned short* p = s_in + r * 264 + c4 * 4;
            p[0] = f2bf(v.x); p[1] = f2bf(v.y); p[2] = f2bf(v.z); p[3] = f2bf(v.w);
        }
        __syncthreads();

        // t1: K=3, CIN=256 -> 24 chunks
        f32x4 acc[2];
#pragma unroll
        for (int n = 0; n < 2; ++n) acc[n] = {0.f, 0.f, 0.f, 0.f};
#pragma unroll 8
        for (int c = 0; c < 24; ++c) {
            const int k  = c >> 3;
            const int ci = ((c & 7) << 5) + koff;
            const bf16x8 a = *(const bf16x8*)(s_in + (lr + k) * 264 + ci);
#pragma unroll
            for (int n = 0; n < 2; ++n) {
                const bf16x8 bb = *(const bf16x8*)(wt1 + (((size_t)c * 256 + co0 + n * 16 + lr) << 5) + koff);
                acc[n] = __builtin_amdgcn_mfma_f32_16x16x32_bf16(a, bb, acc[n], 0, 0, 0);
            }
        }
#pragma unroll
        for (int n = 0; n < 2; ++n) {
            const float bv = bt1[co0 + n * 16 + lr];
#pragma unroll
            for (int r = 0; r < 4; ++r)
                s_mid[(lk * 4 + r) * 264 + co0 + n * 16 + lr] = f2bf(fmaxf(acc[n][r] + bv, 0.f));
        }
        __syncthreads();

        // t2: K=1 -> 8 chunks, epilogue to global + norm
        f32x4 a2[2];
#pragma unroll
        for (int n = 0; n < 2; ++n) a2[n] = {0.f, 0.f, 0.f, 0.f};
#pragma unroll
        for (int c = 0; c < 8; ++c) {
            const bf16x8 a = *(const bf16x8*)(s_mid + lr * 264 + (c << 5) + koff);
#pragma unroll
            for (int n = 0; n < 2; ++n) {
                const bf16x8 bb = *(const bf16x8*)(wt2 + (((size_t)c * 256 + co0 + n * 16 + lr) << 5) + koff);
                a2[n] = __builtin_amdgcn_mfma_f32_16x16x32_bf16(a, bb, a2[n], 0, 0, 0);
            }
        }
        float bv2[2];
#pragma unroll
        for (int n = 0; n < 2; ++n) bv2[n] = bt2[co0 + n * 16 + lr];
#pragma unroll
        for (int r = 0; r < 4; ++r) {
            const int row = lk * 4 + r;
            float np = 0.f;
#pragma unroll
            for (int n = 0; n < 2; ++n) {
                const unsigned short h = f2bf(a2[n][r] + bv2[n]);
                tB[((size_t)(b * TTEXT + t0 + row)) * 256 + co0 + n * 16 + lr] = h;
                const float vq = bf2f(h);
                np = fmaf(vq, vq, np);
            }
            np += __shfl_xor(np, 1);
            np += __shfl_xor(np, 2);
            np += __shfl_xor(np, 4);
            np += __shfl_xor(np, 8);
            if (lr == 0) s_red[row][w] = np;
        }
        __syncthreads();
        if (tid < 16) {
            float s4 = 0.f;
#pragma unroll
            for (int ww = 0; ww < 8; ++ww) s4 += s_red[tid][ww];
            tnorm[b * TTEXT + t0 + tid] = s4;
        }
        __syncthreads();
        __threadfence();                       // release tB + tnorm
        if (tid == 0) atomicAdd(&flags[b], 1);
        return;
    }

    // ------------------------- feats stem -------------------------
    const int fb = bid - 40;
    const int b  = fb & 3;
    const int t0 = (fb >> 2) << 4;
    unsigned short* s_fin = s;          // [20][104]
    unsigned short* s_b1  = s + 2080;   // [18][264]
    unsigned short* s_b2  = s + 6832;   // [16][264]
    unsigned short* s_out = s;          // [16][264] overlays s_fin/s_b1 (dead after f2)

    for (int idx = tid; idx < 20 * 24; idx += 512) {
        const int r  = idx / 24, c4 = idx - r * 24;
        const int ch = c4 * 4;
        const int x  = t0 - 2 + r;
        float4 v = {0.f, 0.f, 0.f, 0.f};
        if (ch < 80 && x >= 0 && x < TFEAT)
            v = *(const float4*)(feats + ((size_t)(b * TFEAT + x)) * 80 + ch);
        unsigned short* p = s_fin + r * 104 + ch;
        p[0] = f2bf(v.x); p[1] = f2bf(v.y); p[2] = f2bf(v.z); p[3] = f2bf(v.w);
    }
    __syncthreads();

    // f1: K=3, CINP=96 -> 9 chunks; 18 output rows (2 M-frags, masked)
    f32x4 acc1[2][2];
#pragma unroll
    for (int m = 0; m < 2; ++m)
#pragma unroll
        for (int n = 0; n < 2; ++n) acc1[m][n] = {0.f, 0.f, 0.f, 0.f};
#pragma unroll
    for (int c = 0; c < 9; ++c) {
        const int k  = c / 3;
        const int ci = (c - k * 3) * 32 + koff;
        bf16x8 a[2];
#pragma unroll
        for (int m = 0; m < 2; ++m) {
            int rr = m * 16 + lr + k;
            if (rr > 19) rr = 19;   // clamp; rows >=18 masked at write
            a[m] = *(const bf16x8*)(s_fin + rr * 104 + ci);
        }
#pragma unroll
        for (int n = 0; n < 2; ++n) {
            const bf16x8 bb = *(const bf16x8*)(wf1 + (((size_t)c * 256 + co0 + n * 16 + lr) << 5) + koff);
            acc1[0][n] = __builtin_amdgcn_mfma_f32_16x16x32_bf16(a[0], bb, acc1[0][n], 0, 0, 0);
            acc1[1][n] = __builtin_amdgcn_mfma_f32_16x16x32_bf16(a[1], bb, acc1[1][n], 0, 0, 0);
        }
    }
#pragma unroll
    for (int n = 0; n < 2; ++n) {
        const float bv = bf1v[co0 + n * 16 + lr];
#pragma unroll
        for (int m = 0; m < 2; ++m)
#pragma unroll
            for (int r = 0; r < 4; ++r) {
                const int i = m * 16 + lk * 4 + r;
                if (i < 18)
                    s_b1[i * 264 + co0 + n * 16 + lr] = f2bf(fmaxf(acc1[m][n][r] + bv, 0.f));
            }
    }
    __syncthreads();

    // f2: K=3, CIN=256 -> 24 chunks
    f32x4 acc2[2];
#pragma unroll
    for (int n = 0; n < 2; ++n) acc2[n] = {0.f, 0.f, 0.f, 0.f};
#pragma unroll 8
    for (int c = 0; c < 24; ++c) {
        const int k  = c >> 3;
        const int ci = ((c & 7) << 5) + koff;
        const bf16x8 a = *(const bf16x8*)(s_b1 + (lr + k) * 264 + ci);
#pragma unroll
        for (int n = 0; n < 2; ++n) {
            const bf16x8 bb = *(const bf16x8*)(wf2 + (((size_t)c * 256 + co0 + n * 16 + lr) << 5) + koff);
            acc2[n] = __builtin_amdgcn_mfma_f32_16x16x32_bf16(a, bb, acc2[n], 0, 0, 0);
        }
    }
#pragma unroll
    for (int n = 0; n < 2; ++n) {
        const float bv = bf2v[co0 + n * 16 + lr];
#pragma unroll
        for (int r = 0; r < 4; ++r)
            s_b2[(lk * 4 + r) * 264 + co0 + n * 16 + lr] = f2bf(fmaxf(acc2[n][r] + bv, 0.f));
    }
    __syncthreads();

    // f3: K=1 -> 8 chunks; output -> LDS s_out, norms -> s_fn
    f32x4 a3[2];
#pragma unroll
    for (int n = 0; n < 2; ++n) a3[n] = {0.f, 0.f, 0.f, 0.f};
#pragma unroll
    for (int c = 0; c < 8; ++c) {
        const bf16x8 a = *(const bf16x8*)(s_b2 + lr * 264 + (c << 5) + koff);
#pragma unroll
        for (int n = 0; n < 2; ++n) {
            const bf16x8 bb = *(const bf16x8*)(wf3 + (((size_t)c * 256 + co0 + n * 16 + lr) << 5) + koff);
            a3[n] = __builtin_amdgcn_mfma_f32_16x16x32_bf16(a, bb, a3[n], 0, 0, 0);
        }
    }
    float bv3[2];
#pragma unroll
    for (int n = 0; n < 2; ++n) bv3[n] = bf3v[co0 + n * 16 + lr];
#pragma unroll
    for (int r = 0; r < 4; ++r) {
        const int row = lk * 4 + r;
        float np = 0.f;
#pragma unroll
        for (int n = 0; n < 2; ++n) {
            const unsigned short h = f2bf(a3[n][r] + bv3[n]);
            s_out[row * 264 + co0 + n * 16 + lr] = h;
            const float vq = bf2f(h);
            np = fmaf(vq, vq, np);
        }
        np += __shfl_xor(np, 1);
        np += __shfl_xor(np, 2);
        np += __shfl_xor(np, 4);
        np += __shfl_xor(np, 8);
        if (lr == 0) s_red[row][w] = np;
    }
    __syncthreads();
    if (tid < 16) {
        float s4 = 0.f;
#pragma unroll
        for (int ww = 0; ww < 8; ++ww) s4 += s_red[tid][ww];
        s_fn[tid] = s4;
    }

    // -------- wait for this batch's 10 text blocks --------
    if (tid == 0) {
        while (atomicAdd(&flags[b], 0) < 10) __builtin_amdgcn_s_sleep(2);
    }
    __syncthreads();
    __threadfence();                        // acquire tB + tnorm

    // ------------------------- score phase -------------------------
    // wave w handles N-frags {w} and (w<2 ? {w+8} : none)
    const int NI = (w < 2) ? 2 : 1;
    const int i0 = t0;

    f32x4 acc[2];
#pragma unroll
    for (int ni = 0; ni < 2; ++ni) acc[ni] = {0.f, 0.f, 0.f, 0.f};
    const unsigned short* __restrict__ Tp = tB + ((size_t)b * TTEXT) * 256;

#pragma unroll
    for (int c = 0; c < 8; ++c) {
        const int d = c * 32 + koff;
        const bf16x8 a = *(const bf16x8*)(s_out + lr * 264 + d);
#pragma unroll
        for (int ni = 0; ni < 2; ++ni) {
            if (ni < NI) {
                const int n = w + ni * 8;
                const bf16x8 bb = *(const bf16x8*)(Tp + ((size_t)(n * 16 + lr)) * 256 + d);
                acc[ni] = __builtin_amdgcn_mfma_f32_16x16x32_bf16(a, bb, acc[ni], 0, 0, 0);
            }
        }
    }

    float fn[4];
#pragma unroll
    for (int r = 0; r < 4; ++r) fn[r] = s_fn[lk * 4 + r];
    float tn[2]; bool mk[2];
#pragma unroll
    for (int ni = 0; ni < 2; ++ni) {
        if (ni < NI) {
            const int j = (w + ni * 8) * 16 + lr;
            tn[ni] = tnorm[b * TTEXT + j];
            mk[ni] = xmask[b * TTEXT + j] != 0;
        } else { tn[ni] = 0.f; mk[ni] = true; }
    }
    float sc[2][4];
#pragma unroll
    for (int ni = 0; ni < 2; ++ni)
#pragma unroll
        for (int r = 0; r < 4; ++r) {
            const float d2 = fn[r] + tn[ni] - 2.0f * acc[ni][r];
            const float sv = -sqrtf(fmaxf(d2, 0.0f));
            sc[ni][r] = mk[ni] ? -INFINITY : sv;
        }

    // pass 1: wave-local max per row
#pragma unroll
    for (int r = 0; r < 4; ++r) {
        float mx = fmaxf(sc[0][r], sc[1][r]);
        mx = fmaxf(mx, __shfl_xor(mx, 1));
        mx = fmaxf(mx, __shfl_xor(mx, 2));
        mx = fmaxf(mx, __shfl_xor(mx, 4));
        mx = fmaxf(mx, __shfl_xor(mx, 8));
        if (lr == 0) s_red[lk * 4 + r][w] = mx;
    }
    __syncthreads();
    // pass 2: global max + wave-local exp-sum
    float gmax[4];
#pragma unroll
    for (int r = 0; r < 4; ++r) {
        const int row = lk * 4 + r;
        float g = s_red[row][0];
#pragma unroll
        for (int ww = 1; ww < 8; ++ww) g = fmaxf(g, s_red[row][ww]);
        gmax[r] = g;
        float sm = 0.f;
#pragma unroll
        for (int ni = 0; ni < 2; ++ni)
            if (ni < NI) sm += expf(sc[ni][r] - g);
        sm += __shfl_xor(sm, 1);
        sm += __shfl_xor(sm, 2);
        sm += __shfl_xor(sm, 4);
        sm += __shfl_xor(sm, 8);
        if (lr == 0) s_red2[row][w] = sm;
    }
    __syncthreads();

    const float cst = lg[161] - lg[961] + lg[801];
#pragma unroll
    for (int r = 0; r < 4; ++r) {
        const int row = lk * 4 + r;
        float ssum = s_red2[row][0];
#pragma unroll
        for (int ww = 1; ww < 8; ++ww) ssum += s_red2[row][ww];
        const float lse = gmax[r] + logf(ssum);
        const int grow = i0 + row;
        const float rowterm = cst - lg[grow + 1] - lg[801 - grow];
#pragma unroll
        for (int ni = 0; ni < 2; ++ni) {
            if (ni < NI) {
                const int j = (w + ni * 8) * 16 + lr;
                const float prior = rowterm - lg[j + 1] - lg[160 - j]
                                  + lg[grow + j + 1] + lg[960 - grow - j];
                out[((size_t)(b * TFEAT + grow)) * TTEXT + j] = sc[ni][r] - lse + prior;
            }
        }
    }
}

extern "C" void kernel_launch(void* const* d_in, const int* in_sizes, int n_in,
                              void* d_out, int out_size, void* d_ws, size_t ws_size,
                              hipStream_t stream) {
    const float* text  = (const float*)d_in[0];
    const float* feats = (const float*)d_in[1];
    const unsigned char* xmask = (const unsigned char*)d_in[4];
    const float* t_w1 = (const float*)d_in[5];
    const float* t_b1 = (const float*)d_in[6];
    const float* t_w2 = (const float*)d_in[7];
    const float* t_b2 = (const float*)d_in[8];
    const float* f_w1 = (const float*)d_in[9];
    const float* f_b1 = (const float*)d_in[10];
    const float* f_w2 = (const float*)d_in[11];
    const float* f_b2 = (const float*)d_in[12];
    const float* f_w3 = (const float*)d_in[13];
    const float* f_b3 = (const float*)d_in[14];
    float* out = (float*)d_out;

    char* wp = (char*)d_ws;
    auto alloc = [&](size_t bytes) -> void* {
        void* p = wp; wp += (bytes + 255) & ~(size_t)255; return p;
    };
    float* lg = (float*)alloc(1024 * 4);
    unsigned short* wb_t1 = (unsigned short*)alloc(196608 * 2);
    unsigned short* wb_t2 = (unsigned short*)alloc(65536 * 2);
    unsigned short* wb_f1 = (unsigned short*)alloc(73728 * 2);
    unsigned short* wb_f2 = (unsigned short*)alloc(196608 * 2);
    unsigned short* wb_f3 = (unsigned short*)alloc(65536 * 2);
    unsigned short* tB = (unsigned short*)alloc((size_t)NB * TTEXT * 256 * 2);
    float* tnorm = (float*)alloc((size_t)NB * TTEXT * 4);
    int* flags = (int*)alloc(64);

    prep_kernel<<<2340, 256, 0, stream>>>(
        t_w1, t_w2, f_w1, f_w2, f_w3, wb_t1, wb_t2, wb_f1, wb_f2, wb_f3, lg, flags);

    fused_kernel<<<240, 512, 0, stream>>>(
        text, feats, xmask,
        wb_t1, t_b1, wb_t2, t_b2,
        wb_f1, f_b1, wb_f2, f_b2, wb_f3, f_b3,
        lg, tB, tnorm, flags, out);
}

// Round 8
// 33.959 us; speedup vs baseline: 1.8061x; 1.8061x over previous
//
#include <hip/hip_runtime.h>
#include <math.h>

#define NB 4
#define TTEXT 160
#define TFEAT 800

typedef __bf16 bf16x8 __attribute__((ext_vector_type(8)));
typedef float f32x4 __attribute__((ext_vector_type(4)));

__device__ inline unsigned short f2bf(float f) {
    unsigned int u = __builtin_bit_cast(unsigned int, f);
    unsigned int r = u + 0x7fffu + ((u >> 16) & 1u);
    return (unsigned short)(r >> 16);
}
__device__ inline float bf2f(unsigned short h) {
    unsigned int u = ((unsigned int)h) << 16;
    return __builtin_bit_cast(float, u);
}

// ---------------------------------------------------------------------------
// Prep: flat exact-size grid (2340 blocks). Weight transforms into
// B-fragment-native layout Wb[c][co][q] + lgamma table. (round-6 verified)
// ---------------------------------------------------------------------------
__global__ __launch_bounds__(256) void prep_kernel(
    const float* __restrict__ tw1, const float* __restrict__ tw2,
    const float* __restrict__ fw1, const float* __restrict__ fw2,
    const float* __restrict__ fw3,
    unsigned short* __restrict__ wb_t1, unsigned short* __restrict__ wb_t2,
    unsigned short* __restrict__ wb_f1, unsigned short* __restrict__ wb_f2,
    unsigned short* __restrict__ wb_f3, float* __restrict__ lg)
{
    const int u = blockIdx.x * 256 + threadIdx.x;
    if (u >= 598016) {
        const int n = u - 598016;
        if (n < 1024) lg[n] = (n >= 1) ? (float)lgamma((double)n) : 0.0f;
        return;
    }
    int rem = u;
    int CIN, CINP, K; const float* src; unsigned short* dst;
    if (rem < 196608)                  { CIN = 256; CINP = 256; K = 3; src = tw1; dst = wb_t1; }
    else if ((rem -= 196608) < 65536)  { CIN = 256; CINP = 256; K = 1; src = tw2; dst = wb_t2; }
    else if ((rem -= 65536) < 73728)   { CIN = 80;  CINP = 96;  K = 3; src = fw1; dst = wb_f1; }
    else if ((rem -= 73728) < 196608)  { CIN = 256; CINP = 256; K = 3; src = fw2; dst = wb_f2; }
    else { rem -= 196608;                CIN = 256; CINP = 256; K = 1; src = fw3; dst = wb_f3; }
    const int q = rem & 31, coc = rem >> 5, co = coc & 255, c = coc >> 8;
    const int cpk = CINP / 32, k = c / cpk, ci = (c % cpk) * 32 + q;
    const float v = (ci < CIN) ? src[((size_t)co * CIN + ci) * K + k] : 0.0f;
    dst[rem] = f2bf(v);
}

// ---------------------------------------------------------------------------
// Fused stems, 1024 threads = 16 waves; wave w owns 16 output channels
// (1 N-frag). Same tiles / LDS layout / math as the verified round-6
// version — only the channel split across waves changed (4 waves/SIMD).
// ---------------------------------------------------------------------------
__global__ __launch_bounds__(1024) void stems_kernel(
    const float* __restrict__ text, const float* __restrict__ feats,
    const unsigned short* __restrict__ wt1, const float* __restrict__ bt1,
    const unsigned short* __restrict__ wt2, const float* __restrict__ bt2,
    const unsigned short* __restrict__ wf1, const float* __restrict__ bf1v,
    const unsigned short* __restrict__ wf2, const float* __restrict__ bf2v,
    const unsigned short* __restrict__ wf3, const float* __restrict__ bf3v,
    unsigned short* __restrict__ tB, float* __restrict__ tnorm,
    unsigned short* __restrict__ fC, float* __restrict__ fnorm)
{
    __shared__ __align__(16) unsigned short s[11056];
    __shared__ float s_red[16][16];
    const int tid = threadIdx.x;
    const int w  = tid >> 6;        // 0..15
    const int l  = tid & 63;
    const int lr = l & 15;
    const int lk = l >> 4;
    const int co0 = w * 16;         // 16 channels per wave
    const int koff = lk * 8;
    const int bid = blockIdx.x;

    if (bid < 40) {
        // ------------------------- text stem -------------------------
        const int b  = bid & 3;
        const int t0 = (bid >> 2) << 4;
        unsigned short* s_in  = s;          // [18][264]
        unsigned short* s_mid = s + 4752;   // [16][264]

        for (int idx = tid; idx < 18 * 64; idx += 1024) {
            const int r = idx >> 6, c4 = idx & 63;
            const int x = t0 - 1 + r;
            float4 v = {0.f, 0.f, 0.f, 0.f};
            if (x >= 0 && x < TTEXT)
                v = *(const float4*)(text + ((size_t)(b * TTEXT + x)) * 256 + c4 * 4);
            unsigned short* p = s_in + r * 264 + c4 * 4;
            p[0] = f2bf(v.x); p[1] = f2bf(v.y); p[2] = f2bf(v.z); p[3] = f2bf(v.w);
        }
        __syncthreads();

        // t1: K=3, CIN=256 -> 24 chunks
        f32x4 acc = {0.f, 0.f, 0.f, 0.f};
#pragma unroll 8
        for (int c = 0; c < 24; ++c) {
            const int k  = c >> 3;
            const int ci = ((c & 7) << 5) + koff;
            const bf16x8 a = *(const bf16x8*)(s_in + (lr + k) * 264 + ci);
            const bf16x8 bb = *(const bf16x8*)(wt1 + (((size_t)c * 256 + co0 + lr) << 5) + koff);
            acc = __builtin_amdgcn_mfma_f32_16x16x32_bf16(a, bb, acc, 0, 0, 0);
        }
        {
            const float bv = bt1[co0 + lr];
#pragma unroll
            for (int r = 0; r < 4; ++r)
                s_mid[(lk * 4 + r) * 264 + co0 + lr] = f2bf(fmaxf(acc[r] + bv, 0.f));
        }
        __syncthreads();

        // t2: K=1 -> 8 chunks, epilogue to global + norm
        f32x4 a2 = {0.f, 0.f, 0.f, 0.f};
#pragma unroll
        for (int c = 0; c < 8; ++c) {
            const bf16x8 a = *(const bf16x8*)(s_mid + lr * 264 + (c << 5) + koff);
            const bf16x8 bb = *(const bf16x8*)(wt2 + (((size_t)c * 256 + co0 + lr) << 5) + koff);
            a2 = __builtin_amdgcn_mfma_f32_16x16x32_bf16(a, bb, a2, 0, 0, 0);
        }
        const float bv2 = bt2[co0 + lr];
#pragma unroll
        for (int r = 0; r < 4; ++r) {
            const int row = lk * 4 + r;
            const unsigned short h = f2bf(a2[r] + bv2);
            tB[((size_t)(b * TTEXT + t0 + row)) * 256 + co0 + lr] = h;
            const float vq = bf2f(h);
            float np = vq * vq;
            np += __shfl_xor(np, 1);
            np += __shfl_xor(np, 2);
            np += __shfl_xor(np, 4);
            np += __shfl_xor(np, 8);
            if (lr == 0) s_red[row][w] = np;
        }
        __syncthreads();
        if (tid < 16) {
            float s4 = 0.f;
#pragma unroll
            for (int ww = 0; ww < 16; ++ww) s4 += s_red[tid][ww];
            tnorm[b * TTEXT + t0 + tid] = s4;
        }
    } else {
        // ------------------------- feats stem -------------------------
        const int fb = bid - 40;
        const int b  = fb & 3;
        const int t0 = (fb >> 2) << 4;
        unsigned short* s_fin = s;          // [20][104]
        unsigned short* s_b1  = s + 2080;   // [18][264]
        unsigned short* s_b2  = s + 6832;   // [16][264]

        for (int idx = tid; idx < 20 * 24; idx += 1024) {
            const int r  = idx / 24, c4 = idx - r * 24;
            const int ch = c4 * 4;
            const int x  = t0 - 2 + r;
            float4 v = {0.f, 0.f, 0.f, 0.f};
            if (ch < 80 && x >= 0 && x < TFEAT)
                v = *(const float4*)(feats + ((size_t)(b * TFEAT + x)) * 80 + ch);
            unsigned short* p = s_fin + r * 104 + ch;
            p[0] = f2bf(v.x); p[1] = f2bf(v.y); p[2] = f2bf(v.z); p[3] = f2bf(v.w);
        }
        __syncthreads();

        // f1: K=3, CINP=96 -> 9 chunks; 18 output rows (2 M-frags, masked)
        f32x4 acc1[2];
#pragma unroll
        for (int m = 0; m < 2; ++m) acc1[m] = {0.f, 0.f, 0.f, 0.f};
#pragma unroll
        for (int c = 0; c < 9; ++c) {
            const int k  = c / 3;
            const int ci = (c - k * 3) * 32 + koff;
            const bf16x8 bb = *(const bf16x8*)(wf1 + (((size_t)c * 256 + co0 + lr) << 5) + koff);
#pragma unroll
            for (int m = 0; m < 2; ++m) {
                int rr = m * 16 + lr + k;
                if (rr > 19) rr = 19;   // clamp; rows >=18 masked at write
                const bf16x8 a = *(const bf16x8*)(s_fin + rr * 104 + ci);
                acc1[m] = __builtin_amdgcn_mfma_f32_16x16x32_bf16(a, bb, acc1[m], 0, 0, 0);
            }
        }
        {
            const float bv = bf1v[co0 + lr];
#pragma unroll
            for (int m = 0; m < 2; ++m)
#pragma unroll
                for (int r = 0; r < 4; ++r) {
                    const int i = m * 16 + lk * 4 + r;
                    if (i < 18)
                        s_b1[i * 264 + co0 + lr] = f2bf(fmaxf(acc1[m][r] + bv, 0.f));
                }
        }
        __syncthreads();

        // f2: K=3, CIN=256 -> 24 chunks
        f32x4 acc2 = {0.f, 0.f, 0.f, 0.f};
#pragma unroll 8
        for (int c = 0; c < 24; ++c) {
            const int k  = c >> 3;
            const int ci = ((c & 7) << 5) + koff;
            const bf16x8 a = *(const bf16x8*)(s_b1 + (lr + k) * 264 + ci);
            const bf16x8 bb = *(const bf16x8*)(wf2 + (((size_t)c * 256 + co0 + lr) << 5) + koff);
            acc2 = __builtin_amdgcn_mfma_f32_16x16x32_bf16(a, bb, acc2, 0, 0, 0);
        }
        {
            const float bv = bf2v[co0 + lr];
#pragma unroll
            for (int r = 0; r < 4; ++r)
                s_b2[(lk * 4 + r) * 264 + co0 + lr] = f2bf(fmaxf(acc2[r] + bv, 0.f));
        }
        __syncthreads();

        // f3: K=1 -> 8 chunks, epilogue to global + norm
        f32x4 a3 = {0.f, 0.f, 0.f, 0.f};
#pragma unroll
        for (int c = 0; c < 8; ++c) {
            const bf16x8 a = *(const bf16x8*)(s_b2 + lr * 264 + (c << 5) + koff);
            const bf16x8 bb = *(const bf16x8*)(wf3 + (((size_t)c * 256 + co0 + lr) << 5) + koff);
            a3 = __builtin_amdgcn_mfma_f32_16x16x32_bf16(a, bb, a3, 0, 0, 0);
        }
        const float bv3 = bf3v[co0 + lr];
#pragma unroll
        for (int r = 0; r < 4; ++r) {
            const int row = lk * 4 + r;
            const unsigned short h = f2bf(a3[r] + bv3);
            fC[((size_t)(b * TFEAT + t0 + row)) * 256 + co0 + lr] = h;
            const float vq = bf2f(h);
            float np = vq * vq;
            np += __shfl_xor(np, 1);
            np += __shfl_xor(np, 2);
            np += __shfl_xor(np, 4);
            np += __shfl_xor(np, 8);
            if (lr == 0) s_red[row][w] = np;
        }
        __syncthreads();
        if (tid < 16) {
            float s4 = 0.f;
#pragma unroll
            for (int ww = 0; ww < 16; ++ww) s4 += s_red[tid][ww];
            fnorm[b * TFEAT + t0 + tid] = s4;
        }
    }
}

// ---------------------------------------------------------------------------
// Score: 512 threads / 8 waves per block; wave w handles N-frags {w} and
// (w<2 ? {w+8} : none) — the round-7-verified score split, reading F/fnorm
// from global. 2-barrier LDS softmax combine.
// ---------------------------------------------------------------------------
__global__ __launch_bounds__(512) void score_mfma(
    const unsigned short* __restrict__ F, const unsigned short* __restrict__ Tt,
    const float* __restrict__ fnorm, const float* __restrict__ tnorm,
    const unsigned char* __restrict__ xmask, const float* __restrict__ lg,
    float* __restrict__ out)
{
    const int b  = blockIdx.y;
    const int tid = threadIdx.x;
    const int w  = tid >> 6;        // 0..7
    const int l  = tid & 63;
    const int lr = l & 15;
    const int lk = l >> 4;
    const int i0 = blockIdx.x * 16;
    const int NI = (w < 2) ? 2 : 1;

    __shared__ float s_red[16][8];
    __shared__ float s_red2[16][8];

    f32x4 acc[2];
#pragma unroll
    for (int ni = 0; ni < 2; ++ni) acc[ni] = {0.f, 0.f, 0.f, 0.f};

    const unsigned short* __restrict__ Fp = F + ((size_t)(b * TFEAT + i0 + lr)) * 256;
    const unsigned short* __restrict__ Tp = Tt + ((size_t)b * TTEXT) * 256;

#pragma unroll
    for (int c = 0; c < 8; ++c) {
        const int d = c * 32 + lk * 8;
        const bf16x8 a = *(const bf16x8*)(Fp + d);
#pragma unroll
        for (int ni = 0; ni < 2; ++ni) {
            if (ni < NI) {
                const int n = w + ni * 8;
                const bf16x8 bb = *(const bf16x8*)(Tp + ((size_t)(n * 16 + lr)) * 256 + d);
                acc[ni] = __builtin_amdgcn_mfma_f32_16x16x32_bf16(a, bb, acc[ni], 0, 0, 0);
            }
        }
    }

    float fn[4];
#pragma unroll
    for (int r = 0; r < 4; ++r) fn[r] = fnorm[b * TFEAT + i0 + lk * 4 + r];
    float tn[2]; bool mk[2];
#pragma unroll
    for (int ni = 0; ni < 2; ++ni) {
        if (ni < NI) {
            const int j = (w + ni * 8) * 16 + lr;
            tn[ni] = tnorm[b * TTEXT + j];
            mk[ni] = xmask[b * TTEXT + j] != 0;
        } else { tn[ni] = 0.f; mk[ni] = true; }
    }
    float sc[2][4];
#pragma unroll
    for (int ni = 0; ni < 2; ++ni)
#pragma unroll
        for (int r = 0; r < 4; ++r) {
            const float d2 = fn[r] + tn[ni] - 2.0f * acc[ni][r];
            const float sv = -sqrtf(fmaxf(d2, 0.0f));
            sc[ni][r] = mk[ni] ? -INFINITY : sv;
        }

    // pass 1: wave-local max per row
#pragma unroll
    for (int r = 0; r < 4; ++r) {
        float mx = fmaxf(sc[0][r], sc[1][r]);
        mx = fmaxf(mx, __shfl_xor(mx, 1));
        mx = fmaxf(mx, __shfl_xor(mx, 2));
        mx = fmaxf(mx, __shfl_xor(mx, 4));
        mx = fmaxf(mx, __shfl_xor(mx, 8));
        if (lr == 0) s_red[lk * 4 + r][w] = mx;
    }
    __syncthreads();
    // pass 2: global max + wave-local exp-sum
    float gmax[4];
#pragma unroll
    for (int r = 0; r < 4; ++r) {
        const int row = lk * 4 + r;
        float g = s_red[row][0];
#pragma unroll
        for (int ww = 1; ww < 8; ++ww) g = fmaxf(g, s_red[row][ww]);
        gmax[r] = g;
        float sm = 0.f;
#pragma unroll
        for (int ni = 0; ni < 2; ++ni)
            if (ni < NI) sm += expf(sc[ni][r] - g);
        sm += __shfl_xor(sm, 1);
        sm += __shfl_xor(sm, 2);
        sm += __shfl_xor(sm, 4);
        sm += __shfl_xor(sm, 8);
        if (lr == 0) s_red2[row][w] = sm;
    }
    __syncthreads();

    const float cst = lg[161] - lg[961] + lg[801];
#pragma unroll
    for (int r = 0; r < 4; ++r) {
        const int row = lk * 4 + r;
        float ssum = s_red2[row][0];
#pragma unroll
        for (int ww = 1; ww < 8; ++ww) ssum += s_red2[row][ww];
        const float lse = gmax[r] + logf(ssum);
        const int grow = i0 + row;
        const float rowterm = cst - lg[grow + 1] - lg[801 - grow];
#pragma unroll
        for (int ni = 0; ni < 2; ++ni) {
            if (ni < NI) {
                const int j = (w + ni * 8) * 16 + lr;
                const float prior = rowterm - lg[j + 1] - lg[160 - j]
                                  + lg[grow + j + 1] + lg[960 - grow - j];
                out[((size_t)(b * TFEAT + grow)) * TTEXT + j] = sc[ni][r] - lse + prior;
            }
        }
    }
}

extern "C" void kernel_launch(void* const* d_in, const int* in_sizes, int n_in,
                              void* d_out, int out_size, void* d_ws, size_t ws_size,
                              hipStream_t stream) {
    const float* text  = (const float*)d_in[0];
    const float* feats = (const float*)d_in[1];
    const unsigned char* xmask = (const unsigned char*)d_in[4];
    const float* t_w1 = (const float*)d_in[5];
    const float* t_b1 = (const float*)d_in[6];
    const float* t_w2 = (const float*)d_in[7];
    const float* t_b2 = (const float*)d_in[8];
    const float* f_w1 = (const float*)d_in[9];
    const float* f_b1 = (const float*)d_in[10];
    const float* f_w2 = (const float*)d_in[11];
    const float* f_b2 = (const float*)d_in[12];
    const float* f_w3 = (const float*)d_in[13];
    const float* f_b3 = (const float*)d_in[14];
    float* out = (float*)d_out;

    char* wp = (char*)d_ws;
    auto alloc = [&](size_t bytes) -> void* {
        void* p = wp; wp += (bytes + 255) & ~(size_t)255; return p;
    };
    float* lg = (float*)alloc(1024 * 4);
    unsigned short* wb_t1 = (unsigned short*)alloc(196608 * 2);
    unsigned short* wb_t2 = (unsigned short*)alloc(65536 * 2);
    unsigned short* wb_f1 = (unsigned short*)alloc(73728 * 2);
    unsigned short* wb_f2 = (unsigned short*)alloc(196608 * 2);
    unsigned short* wb_f3 = (unsigned short*)alloc(65536 * 2);
    unsigned short* tB = (unsigned short*)alloc((size_t)NB * TTEXT * 256 * 2);
    unsigned short* fC = (unsigned short*)alloc((size_t)NB * TFEAT * 256 * 2);
    float* fnorm = (float*)alloc((size_t)NB * TFEAT * 4);
    float* tnorm = (float*)alloc((size_t)NB * TTEXT * 4);

    prep_kernel<<<2340, 256, 0, stream>>>(
        t_w1, t_w2, f_w1, f_w2, f_w3, wb_t1, wb_t2, wb_f1, wb_f2, wb_f3, lg);

    stems_kernel<<<240, 1024, 0, stream>>>(
        text, feats,
        wb_t1, t_b1, wb_t2, t_b2,
        wb_f1, f_b1, wb_f2, f_b2, wb_f3, f_b3,
        tB, tnorm, fC, fnorm);

    score_mfma<<<dim3(50, NB), 512, 0, stream>>>(fC, tB, fnorm, tnorm, xmask, lg, out);
}

// Round 9
// 33.371 us; speedup vs baseline: 1.8379x; 1.0176x over previous
//
#include <hip/hip_runtime.h>
#include <math.h>

#define NB 4
#define TTEXT 160
#define TFEAT 800

typedef __bf16 bf16x8 __attribute__((ext_vector_type(8)));
typedef float f32x4 __attribute__((ext_vector_type(4)));

__device__ inline unsigned short f2bf(float f) {
    unsigned int u = __builtin_bit_cast(unsigned int, f);
    unsigned int r = u + 0x7fffu + ((u >> 16) & 1u);
    return (unsigned short)(r >> 16);
}
__device__ inline float bf2f(unsigned short h) {
    unsigned int u = ((unsigned int)h) << 16;
    return __builtin_bit_cast(float, u);
}

// f32 lgamma for integer arguments n>=1 (Stirling, n<8 promoted by 8).
// abs err ~1e-3 at n~1000 (f32 rounding), series err ~3e-8.
__device__ inline float lgamma_int(float nf) {
    float z = nf, corr = 0.0f;
    if (nf < 8.0f) {
        const float p = nf * (nf + 1.0f) * (nf + 2.0f) * (nf + 3.0f)
                      * (nf + 4.0f) * (nf + 5.0f) * (nf + 6.0f) * (nf + 7.0f);
        z = nf + 8.0f;
        corr = logf(p);
    }
    const float lz = logf(z);
    const float iz = 1.0f / z;
    const float s = (z - 0.5f) * lz - z + 0.918938533f
                  + iz * (0.0833333333f - iz * iz * 0.00277777778f);
    return s - corr;
}

// ---------------------------------------------------------------------------
// Prep: weights only — flat exact grid (2336 blocks x 256 = 598016 threads),
// B-fragment-native layout Wb[c][co][q]. No f64, no straggler block.
// ---------------------------------------------------------------------------
__global__ __launch_bounds__(256) void prep_kernel(
    const float* __restrict__ tw1, const float* __restrict__ tw2,
    const float* __restrict__ fw1, const float* __restrict__ fw2,
    const float* __restrict__ fw3,
    unsigned short* __restrict__ wb_t1, unsigned short* __restrict__ wb_t2,
    unsigned short* __restrict__ wb_f1, unsigned short* __restrict__ wb_f2,
    unsigned short* __restrict__ wb_f3)
{
    const int u = blockIdx.x * 256 + threadIdx.x;
    int rem = u;
    int CIN, CINP, K; const float* src; unsigned short* dst;
    if (rem < 196608)                  { CIN = 256; CINP = 256; K = 3; src = tw1; dst = wb_t1; }
    else if ((rem -= 196608) < 65536)  { CIN = 256; CINP = 256; K = 1; src = tw2; dst = wb_t2; }
    else if ((rem -= 65536) < 73728)   { CIN = 80;  CINP = 96;  K = 3; src = fw1; dst = wb_f1; }
    else if ((rem -= 73728) < 196608)  { CIN = 256; CINP = 256; K = 3; src = fw2; dst = wb_f2; }
    else { rem -= 196608;                CIN = 256; CINP = 256; K = 1; src = fw3; dst = wb_f3; }
    const int q = rem & 31, coc = rem >> 5, co = coc & 255, c = coc >> 8;
    const int cpk = CINP / 32, k = c / cpk, ci = (c % cpk) * 32 + q;
    const float v = (ci < CIN) ? src[((size_t)co * CIN + ci) * K + k] : 0.0f;
    dst[rem] = f2bf(v);
}

// ---------------------------------------------------------------------------
// Fused stems, 1024 threads = 16 waves; wave w owns 16 output channels
// (1 N-frag). Verified round-8 code, unchanged.
// ---------------------------------------------------------------------------
__global__ __launch_bounds__(1024) void stems_kernel(
    const float* __restrict__ text, const float* __restrict__ feats,
    const unsigned short* __restrict__ wt1, const float* __restrict__ bt1,
    const unsigned short* __restrict__ wt2, const float* __restrict__ bt2,
    const unsigned short* __restrict__ wf1, const float* __restrict__ bf1v,
    const unsigned short* __restrict__ wf2, const float* __restrict__ bf2v,
    const unsigned short* __restrict__ wf3, const float* __restrict__ bf3v,
    unsigned short* __restrict__ tB, float* __restrict__ tnorm,
    unsigned short* __restrict__ fC, float* __restrict__ fnorm)
{
    __shared__ __align__(16) unsigned short s[11056];
    __shared__ float s_red[16][16];
    const int tid = threadIdx.x;
    const int w  = tid >> 6;        // 0..15
    const int l  = tid & 63;
    const int lr = l & 15;
    const int lk = l >> 4;
    const int co0 = w * 16;         // 16 channels per wave
    const int koff = lk * 8;
    const int bid = blockIdx.x;

    if (bid < 40) {
        // ------------------------- text stem -------------------------
        const int b  = bid & 3;
        const int t0 = (bid >> 2) << 4;
        unsigned short* s_in  = s;          // [18][264]
        unsigned short* s_mid = s + 4752;   // [16][264]

        for (int idx = tid; idx < 18 * 64; idx += 1024) {
            const int r = idx >> 6, c4 = idx & 63;
            const int x = t0 - 1 + r;
            float4 v = {0.f, 0.f, 0.f, 0.f};
            if (x >= 0 && x < TTEXT)
                v = *(const float4*)(text + ((size_t)(b * TTEXT + x)) * 256 + c4 * 4);
            unsigned short* p = s_in + r * 264 + c4 * 4;
            p[0] = f2bf(v.x); p[1] = f2bf(v.y); p[2] = f2bf(v.z); p[3] = f2bf(v.w);
        }
        __syncthreads();

        // t1: K=3, CIN=256 -> 24 chunks
        f32x4 acc = {0.f, 0.f, 0.f, 0.f};
#pragma unroll 8
        for (int c = 0; c < 24; ++c) {
            const int k  = c >> 3;
            const int ci = ((c & 7) << 5) + koff;
            const bf16x8 a = *(const bf16x8*)(s_in + (lr + k) * 264 + ci);
            const bf16x8 bb = *(const bf16x8*)(wt1 + (((size_t)c * 256 + co0 + lr) << 5) + koff);
            acc = __builtin_amdgcn_mfma_f32_16x16x32_bf16(a, bb, acc, 0, 0, 0);
        }
        {
            const float bv = bt1[co0 + lr];
#pragma unroll
            for (int r = 0; r < 4; ++r)
                s_mid[(lk * 4 + r) * 264 + co0 + lr] = f2bf(fmaxf(acc[r] + bv, 0.f));
        }
        __syncthreads();

        // t2: K=1 -> 8 chunks, epilogue to global + norm
        f32x4 a2 = {0.f, 0.f, 0.f, 0.f};
#pragma unroll
        for (int c = 0; c < 8; ++c) {
            const bf16x8 a = *(const bf16x8*)(s_mid + lr * 264 + (c << 5) + koff);
            const bf16x8 bb = *(const bf16x8*)(wt2 + (((size_t)c * 256 + co0 + lr) << 5) + koff);
            a2 = __builtin_amdgcn_mfma_f32_16x16x32_bf16(a, bb, a2, 0, 0, 0);
        }
        const float bv2 = bt2[co0 + lr];
#pragma unroll
        for (int r = 0; r < 4; ++r) {
            const int row = lk * 4 + r;
            const unsigned short h = f2bf(a2[r] + bv2);
            tB[((size_t)(b * TTEXT + t0 + row)) * 256 + co0 + lr] = h;
            const float vq = bf2f(h);
            float np = vq * vq;
            np += __shfl_xor(np, 1);
            np += __shfl_xor(np, 2);
            np += __shfl_xor(np, 4);
            np += __shfl_xor(np, 8);
            if (lr == 0) s_red[row][w] = np;
        }
        __syncthreads();
        if (tid < 16) {
            float s4 = 0.f;
#pragma unroll
            for (int ww = 0; ww < 16; ++ww) s4 += s_red[tid][ww];
            tnorm[b * TTEXT + t0 + tid] = s4;
        }
    } else {
        // ------------------------- feats stem -------------------------
        const int fb = bid - 40;
        const int b  = fb & 3;
        const int t0 = (fb >> 2) << 4;
        unsigned short* s_fin = s;          // [20][104]
        unsigned short* s_b1  = s + 2080;   // [18][264]
        unsigned short* s_b2  = s + 6832;   // [16][264]

        for (int idx = tid; idx < 20 * 24; idx += 1024) {
            const int r  = idx / 24, c4 = idx - r * 24;
            const int ch = c4 * 4;
            const int x  = t0 - 2 + r;
            float4 v = {0.f, 0.f, 0.f, 0.f};
            if (ch < 80 && x >= 0 && x < TFEAT)
                v = *(const float4*)(feats + ((size_t)(b * TFEAT + x)) * 80 + ch);
            unsigned short* p = s_fin + r * 104 + ch;
            p[0] = f2bf(v.x); p[1] = f2bf(v.y); p[2] = f2bf(v.z); p[3] = f2bf(v.w);
        }
        __syncthreads();

        // f1: K=3, CINP=96 -> 9 chunks; 18 output rows (2 M-frags, masked)
        f32x4 acc1[2];
#pragma unroll
        for (int m = 0; m < 2; ++m) acc1[m] = {0.f, 0.f, 0.f, 0.f};
#pragma unroll
        for (int c = 0; c < 9; ++c) {
            const int k  = c / 3;
            const int ci = (c - k * 3) * 32 + koff;
            const bf16x8 bb = *(const bf16x8*)(wf1 + (((size_t)c * 256 + co0 + lr) << 5) + koff);
#pragma unroll
            for (int m = 0; m < 2; ++m) {
                int rr = m * 16 + lr + k;
                if (rr > 19) rr = 19;   // clamp; rows >=18 masked at write
                const bf16x8 a = *(const bf16x8*)(s_fin + rr * 104 + ci);
                acc1[m] = __builtin_amdgcn_mfma_f32_16x16x32_bf16(a, bb, acc1[m], 0, 0, 0);
            }
        }
        {
            const float bv = bf1v[co0 + lr];
#pragma unroll
            for (int m = 0; m < 2; ++m)
#pragma unroll
                for (int r = 0; r < 4; ++r) {
                    const int i = m * 16 + lk * 4 + r;
                    if (i < 18)
                        s_b1[i * 264 + co0 + lr] = f2bf(fmaxf(acc1[m][r] + bv, 0.f));
                }
        }
        __syncthreads();

        // f2: K=3, CIN=256 -> 24 chunks
        f32x4 acc2 = {0.f, 0.f, 0.f, 0.f};
#pragma unroll 8
        for (int c = 0; c < 24; ++c) {
            const int k  = c >> 3;
            const int ci = ((c & 7) << 5) + koff;
            const bf16x8 a = *(const bf16x8*)(s_b1 + (lr + k) * 264 + ci);
            const bf16x8 bb = *(const bf16x8*)(wf2 + (((size_t)c * 256 + co0 + lr) << 5) + koff);
            acc2 = __builtin_amdgcn_mfma_f32_16x16x32_bf16(a, bb, acc2, 0, 0, 0);
        }
        {
            const float bv = bf2v[co0 + lr];
#pragma unroll
            for (int r = 0; r < 4; ++r)
                s_b2[(lk * 4 + r) * 264 + co0 + lr] = f2bf(fmaxf(acc2[r] + bv, 0.f));
        }
        __syncthreads();

        // f3: K=1 -> 8 chunks, epilogue to global + norm
        f32x4 a3 = {0.f, 0.f, 0.f, 0.f};
#pragma unroll
        for (int c = 0; c < 8; ++c) {
            const bf16x8 a = *(const bf16x8*)(s_b2 + lr * 264 + (c << 5) + koff);
            const bf16x8 bb = *(const bf16x8*)(wf3 + (((size_t)c * 256 + co0 + lr) << 5) + koff);
            a3 = __builtin_amdgcn_mfma_f32_16x16x32_bf16(a, bb, a3, 0, 0, 0);
        }
        const float bv3 = bf3v[co0 + lr];
#pragma unroll
        for (int r = 0; r < 4; ++r) {
            const int row = lk * 4 + r;
            const unsigned short h = f2bf(a3[r] + bv3);
            fC[((size_t)(b * TFEAT + t0 + row)) * 256 + co0 + lr] = h;
            const float vq = bf2f(h);
            float np = vq * vq;
            np += __shfl_xor(np, 1);
            np += __shfl_xor(np, 2);
            np += __shfl_xor(np, 4);
            np += __shfl_xor(np, 8);
            if (lr == 0) s_red[row][w] = np;
        }
        __syncthreads();
        if (tid < 16) {
            float s4 = 0.f;
#pragma unroll
            for (int ww = 0; ww < 16; ++ww) s4 += s_red[tid][ww];
            fnorm[b * TFEAT + t0 + tid] = s4;
        }
    }
}

// ---------------------------------------------------------------------------
// Score: 512 threads / 8 waves per block; wave w handles N-frags {w} and
// (w<2 ? {w+8} : none). Phase 0 builds the integer-lgamma table in LDS via
// f32 Stirling (no global lg dependency). 2-barrier LDS softmax combine.
// ---------------------------------------------------------------------------
__global__ __launch_bounds__(512) void score_mfma(
    const unsigned short* __restrict__ F, const unsigned short* __restrict__ Tt,
    const float* __restrict__ fnorm, const float* __restrict__ tnorm,
    const unsigned char* __restrict__ xmask,
    float* __restrict__ out)
{
    const int b  = blockIdx.y;
    const int tid = threadIdx.x;
    const int w  = tid >> 6;        // 0..7
    const int l  = tid & 63;
    const int lr = l & 15;
    const int lk = l >> 4;
    const int i0 = blockIdx.x * 16;
    const int NI = (w < 2) ? 2 : 1;

    __shared__ float s_lg[962];
    __shared__ float s_red[16][8];
    __shared__ float s_red2[16][8];

    // phase 0: integer lgamma table (f32 Stirling)
    for (int idx = tid; idx < 962; idx += 512)
        s_lg[idx] = (idx >= 1) ? lgamma_int((float)idx) : 0.0f;

    f32x4 acc[2];
#pragma unroll
    for (int ni = 0; ni < 2; ++ni) acc[ni] = {0.f, 0.f, 0.f, 0.f};

    const unsigned short* __restrict__ Fp = F + ((size_t)(b * TFEAT + i0 + lr)) * 256;
    const unsigned short* __restrict__ Tp = Tt + ((size_t)b * TTEXT) * 256;

#pragma unroll
    for (int c = 0; c < 8; ++c) {
        const int d = c * 32 + lk * 8;
        const bf16x8 a = *(const bf16x8*)(Fp + d);
#pragma unroll
        for (int ni = 0; ni < 2; ++ni) {
            if (ni < NI) {
                const int n = w + ni * 8;
                const bf16x8 bb = *(const bf16x8*)(Tp + ((size_t)(n * 16 + lr)) * 256 + d);
                acc[ni] = __builtin_amdgcn_mfma_f32_16x16x32_bf16(a, bb, acc[ni], 0, 0, 0);
            }
        }
    }

    float fn[4];
#pragma unroll
    for (int r = 0; r < 4; ++r) fn[r] = fnorm[b * TFEAT + i0 + lk * 4 + r];
    float tn[2]; bool mk[2];
#pragma unroll
    for (int ni = 0; ni < 2; ++ni) {
        if (ni < NI) {
            const int j = (w + ni * 8) * 16 + lr;
            tn[ni] = tnorm[b * TTEXT + j];
            mk[ni] = xmask[b * TTEXT + j] != 0;
        } else { tn[ni] = 0.f; mk[ni] = true; }
    }
    float sc[2][4];
#pragma unroll
    for (int ni = 0; ni < 2; ++ni)
#pragma unroll
        for (int r = 0; r < 4; ++r) {
            const float d2 = fn[r] + tn[ni] - 2.0f * acc[ni][r];
            const float sv = -sqrtf(fmaxf(d2, 0.0f));
            sc[ni][r] = mk[ni] ? -INFINITY : sv;
        }

    // pass 1: wave-local max per row
#pragma unroll
    for (int r = 0; r < 4; ++r) {
        float mx = fmaxf(sc[0][r], sc[1][r]);
        mx = fmaxf(mx, __shfl_xor(mx, 1));
        mx = fmaxf(mx, __shfl_xor(mx, 2));
        mx = fmaxf(mx, __shfl_xor(mx, 4));
        mx = fmaxf(mx, __shfl_xor(mx, 8));
        if (lr == 0) s_red[lk * 4 + r][w] = mx;
    }
    __syncthreads();
    // pass 2: global max + wave-local exp-sum
    float gmax[4];
#pragma unroll
    for (int r = 0; r < 4; ++r) {
        const int row = lk * 4 + r;
        float g = s_red[row][0];
#pragma unroll
        for (int ww = 1; ww < 8; ++ww) g = fmaxf(g, s_red[row][ww]);
        gmax[r] = g;
        float sm = 0.f;
#pragma unroll
        for (int ni = 0; ni < 2; ++ni)
            if (ni < NI) sm += expf(sc[ni][r] - g);
        sm += __shfl_xor(sm, 1);
        sm += __shfl_xor(sm, 2);
        sm += __shfl_xor(sm, 4);
        sm += __shfl_xor(sm, 8);
        if (lr == 0) s_red2[row][w] = sm;
    }
    __syncthreads();

    const float cst = s_lg[161] - s_lg[961] + s_lg[801];
#pragma unroll
    for (int r = 0; r < 4; ++r) {
        const int row = lk * 4 + r;
        float ssum = s_red2[row][0];
#pragma unroll
        for (int ww = 1; ww < 8; ++ww) ssum += s_red2[row][ww];
        const float lse = gmax[r] + logf(ssum);
        const int grow = i0 + row;
        const float rowterm = cst - s_lg[grow + 1] - s_lg[801 - grow];
#pragma unroll
        for (int ni = 0; ni < 2; ++ni) {
            if (ni < NI) {
                const int j = (w + ni * 8) * 16 + lr;
                const float prior = rowterm - s_lg[j + 1] - s_lg[160 - j]
                                  + s_lg[grow + j + 1] + s_lg[960 - grow - j];
                out[((size_t)(b * TFEAT + grow)) * TTEXT + j] = sc[ni][r] - lse + prior;
            }
        }
    }
}

extern "C" void kernel_launch(void* const* d_in, const int* in_sizes, int n_in,
                              void* d_out, int out_size, void* d_ws, size_t ws_size,
                              hipStream_t stream) {
    const float* text  = (const float*)d_in[0];
    const float* feats = (const float*)d_in[1];
    const unsigned char* xmask = (const unsigned char*)d_in[4];
    const float* t_w1 = (const float*)d_in[5];
    const float* t_b1 = (const float*)d_in[6];
    const float* t_w2 = (const float*)d_in[7];
    const float* t_b2 = (const float*)d_in[8];
    const float* f_w1 = (const float*)d_in[9];
    const float* f_b1 = (const float*)d_in[10];
    const float* f_w2 = (const float*)d_in[11];
    const float* f_b2 = (const float*)d_in[12];
    const float* f_w3 = (const float*)d_in[13];
    const float* f_b3 = (const float*)d_in[14];
    float* out = (float*)d_out;

    char* wp = (char*)d_ws;
    auto alloc = [&](size_t bytes) -> void* {
        void* p = wp; wp += (bytes + 255) & ~(size_t)255; return p;
    };
    unsigned short* wb_t1 = (unsigned short*)alloc(196608 * 2);
    unsigned short* wb_t2 = (unsigned short*)alloc(65536 * 2);
    unsigned short* wb_f1 = (unsigned short*)alloc(73728 * 2);
    unsigned short* wb_f2 = (unsigned short*)alloc(196608 * 2);
    unsigned short* wb_f3 = (unsigned short*)alloc(65536 * 2);
    unsigned short* tB = (unsigned short*)alloc((size_t)NB * TTEXT * 256 * 2);
    unsigned short* fC = (unsigned short*)alloc((size_t)NB * TFEAT * 256 * 2);
    float* fnorm = (float*)alloc((size_t)NB * TFEAT * 4);
    float* tnorm = (float*)alloc((size_t)NB * TTEXT * 4);

    prep_kernel<<<2336, 256, 0, stream>>>(
        t_w1, t_w2, f_w1, f_w2, f_w3, wb_t1, wb_t2, wb_f1, wb_f2, wb_f3);

    stems_kernel<<<240, 1024, 0, stream>>>(
        text, feats,
        wb_t1, t_b1, wb_t2, t_b2,
        wb_f1, f_b1, wb_f2, f_b2, wb_f3, f_b3,
        tB, tnorm, fC, fnorm);

    score_mfma<<<dim3(50, NB), 512, 0, stream>>>(fC, tB, fnorm, tnorm, xmask, out);
}